// Round 22
// baseline (204.633 us; speedup 1.0000x reference)
//
#include <hip/hip_runtime.h>
#include <math.h>

#define NN 50000
#define NE 800000
#define DD 128
#define LL 4
#define OUTD 40
#define NB_IN ((NN + 31) / 32)               // 1563 input blocks (dispatched FIRST)
#define NB_T 256                              // build_T blocks (2 rows each)
#define NB_SC ((NE + 1023) / 1024)           // 782 scatter blocks, 4 edges/thread
#define MAXD 64                               // fixed slot count per node (max deg ~45)

// S(t) = sigmoid(10*(elu(t) - 0.5)), matching jax.nn.elu (expm1) + sigmoid
__device__ __forceinline__ float S_func(float t) {
    float z = (t > 0.0f) ? t : expm1f(t);
    float xx = 10.0f * (z - 0.5f);
    return 1.0f / (1.0f + expf(-xx));
}

// ---- fused front kernel: input GEMM || build_T || single-pass slot scatter ----
// R22: GEMM tile 64->32 nodes (1563 blocks, 4n x 4c per thread) — front is
// latency-bound on the GEMM arm's per-block critical path (R20 counters: no
// pipe >35% busy at full occupancy); halving per-block work shortens the tail.
// R21's uint16-slots/byte-idx repacking was neutral (random gathers touch one
// line regardless of width) — reverted to R20's int layout.
__global__ __launch_bounds__(256) void front_kernel(
        const float* __restrict__ W_layers, float* __restrict__ T0,
        float* __restrict__ Delta,
        const float* __restrict__ x, const float* __restrict__ W_in,
        const float* __restrict__ b_in, int* __restrict__ idx0,
        const int* __restrict__ src, const int* __restrict__ dst,
        unsigned int* __restrict__ cursor, int* __restrict__ slots) {
    __shared__ float wlds[16][128];
    __shared__ float xls[32][20];
    int t = threadIdx.x;

    if (blockIdx.x >= NB_IN) {
        if (blockIdx.x < NB_IN + NB_T) {
            // ---- build_T: 2 (l,d) rows per block ----
            int bd = (blockIdx.x - NB_IN) * 2 + (t >> 7);
            int l = bd >> 7, d = bd & 127;
            int j = t & 127;
            const float* W2 = W_layers + ((size_t)l * 1408 + 128 + (size_t)d * 10) * 128;
            float w[10];
            #pragma unroll
            for (int y = 0; y < 10; ++y) w[y] = W2[(size_t)y * 128 + j];
            float t0 = 0.0f;
            #pragma unroll
            for (int y = 0; y < 10; ++y) t0 += S_func((float)(0 - y)) * w[y];
            T0[(size_t)bd * 128 + j] = t0;
            for (int c = 1; c <= 10; ++c) {
                float tc = 0.0f;
                #pragma unroll
                for (int y = 0; y < 10; ++y) tc += S_func((float)(c - y)) * w[y];
                Delta[((size_t)bd * 10 + (c - 1)) * 128 + j] = tc - t0;
            }
        } else {
            // ---- single-pass slot scatter, 4 edges/thread ----
            int e0 = (blockIdx.x - NB_IN - NB_T) * 1024 + t;
            #pragma unroll
            for (int k = 0; k < 4; ++k) {
                int e = e0 + k * 256;
                if (e < NE) {
                    int d = dst[e];
                    int s = src[e];
                    unsigned int pos = atomicAdd(&cursor[d], 1u);
                    if (pos < MAXD) slots[(size_t)d * MAXD + pos] = s;
                }
            }
        }
        return;
    }

    // ---- input GEMM: 32 nodes x 128 cols per block, 4 nodes x 4 cols/thread.
    // cg = t&31 -> cols cg*4..cg*4+3; ng = t>>5 -> nodes n0+ng*4+i.
    // Per-(n,j) chain kc->kk4->q ascending (k = 0..127 in order), single
    // accumulator -> bit-identical to all passing rounds. Epilogue = R10's
    // proven 32-lane butterfly.
    int bb = blockIdx.x;
    int cg = t & 31;
    int ng = t >> 5;
    int n0 = bb * 32;
    float acc[4][4];
    #pragma unroll
    for (int i = 0; i < 4; ++i)
        #pragma unroll
        for (int r = 0; r < 4; ++r) acc[i][r] = 0.0f;

    for (int kc = 0; kc < 8; ++kc) {
        __syncthreads();
        #pragma unroll
        for (int p = 0; p < 2; ++p) {
            int f = t + p * 256;           // float4 id in [0,512): 16 rows x 32
            int kr = f >> 5, c4 = f & 31;
            *(float4*)&wlds[kr][c4 * 4] =
                *(const float4*)&W_in[(size_t)(kc * 16 + kr) * 128 + c4 * 4];
        }
        if (t < 128) {
            int node = t >> 2, k4 = t & 3; // 32 nodes x 4 float4 of 16 k
            int gn = n0 + node;
            if (gn > NN - 1) gn = NN - 1;
            *(float4*)&xls[node][k4 * 4] =
                *(const float4*)&x[(size_t)gn * 128 + kc * 16 + k4 * 4];
        }
        __syncthreads();
        #pragma unroll
        for (int kk4 = 0; kk4 < 4; ++kk4) {
            float4 xv[4];
            #pragma unroll
            for (int i = 0; i < 4; ++i)
                xv[i] = *(const float4*)&xls[ng * 4 + i][kk4 * 4];
            #pragma unroll
            for (int q = 0; q < 4; ++q) {
                int k = kk4 * 4 + q;
                float4 w1 = *(const float4*)&wlds[k][cg * 4];
                #pragma unroll
                for (int i = 0; i < 4; ++i) {
                    float xvv = (q == 0) ? xv[i].x : (q == 1) ? xv[i].y
                              : (q == 2) ? xv[i].z : xv[i].w;
                    acc[i][0] = fmaf(xvv, w1.x, acc[i][0]);
                    acc[i][1] = fmaf(xvv, w1.y, acc[i][1]);
                    acc[i][2] = fmaf(xvv, w1.z, acc[i][2]);
                    acc[i][3] = fmaf(xvv, w1.w, acc[i][3]);
                }
            }
        }
    }
    float4 b1 = *(const float4*)&b_in[cg * 4];
    #pragma unroll
    for (int i = 0; i < 4; ++i) {
        float v0 = acc[i][0] + b1.x, v1 = acc[i][1] + b1.y;
        float v2 = acc[i][2] + b1.z, v3 = acc[i][3] + b1.w;
        float bv = v0; int bi = cg * 4;
        if (v1 > bv) { bv = v1; bi = cg * 4 + 1; }
        if (v2 > bv) { bv = v2; bi = cg * 4 + 2; }
        if (v3 > bv) { bv = v3; bi = cg * 4 + 3; }
        #pragma unroll
        for (int o = 16; o >= 1; o >>= 1) {
            float ov = __shfl_xor(bv, o);
            int oi = __shfl_xor(bi, o);
            if (ov > bv || (ov == bv && oi < bi)) { bv = ov; bi = oi; }
        }
        int n = n0 + ng * 4 + i;
        if (cg == 0 && n < NN) idx0[n] = bi;
    }
}

__global__ void build_Base(const float* __restrict__ T0, float* __restrict__ Base) {
    int l = blockIdx.x, j = threadIdx.x;
    float s = 0.0f;
    for (int d = 0; d < 128; ++d) s += T0[((size_t)l * 128 + d) * 128 + j];
    Base[l * 128 + j] = s;
}

// ---- fused per-layer kernel: half-wave (32 lanes) per node, 8 nodes/block.
// cnt accessed ONLY as scalar uint (R3 TBAA lesson); per-half-wave phases
// syncless. LAST fuses the 40-logit log_softmax epilogue.
template<bool LAST>
__global__ __launch_bounds__(256) void layer_kernel(
        const unsigned int* __restrict__ cursor, const int* __restrict__ slots,
        const float* __restrict__ Wl, const float* __restrict__ bl,
        const float* __restrict__ Delta_l, const float* __restrict__ Base_l,
        const int* __restrict__ idx_in, int* __restrict__ idx_out,
        const int* __restrict__ idx_all, const float* __restrict__ W_out,
        const float* __restrict__ b_out, float* __restrict__ out) {
    __shared__ unsigned int cnt[8][128];
    __shared__ int list[8][128];
    int w = threadIdx.x >> 6;
    int lane = threadIdx.x & 63;
    int h = lane >> 5, l = lane & 31;
    int nidx = w * 2 + h;
    int n = blockIdx.x * 8 + nidx;
    unsigned int deg = cursor[n];
    if (deg > MAXD) deg = MAXD;
    int hidx = idx_in[n];
    int id0, id1, id2;
    if (LAST) {
        id0 = idx_all[n];
        id1 = idx_all[NN + n];
        id2 = idx_all[2 * NN + n];
    }
    float4 wv = *(const float4*)((const char*)Wl + (size_t)hidx * 512 + l * 16);
    float4 bs = *(const float4*)((const char*)Base_l + l * 16);
    float4 bb = *(const float4*)((const char*)bl + l * 16);
    cnt[nidx][l]      = 0u;
    cnt[nidx][l + 32] = 0u;
    cnt[nidx][l + 64] = 0u;
    cnt[nidx][l + 96] = 0u;
    const int* srow = slots + (size_t)n * MAXD;
    for (unsigned int e = l; e < deg; e += 32u) {
        int s = srow[e];
        atomicAdd(&cnt[nidx][idx_in[s]], 1u);
    }
    unsigned int c0 = cnt[nidx][4 * l];
    unsigned int c1 = cnt[nidx][4 * l + 1];
    unsigned int c2 = cnt[nidx][4 * l + 2];
    unsigned int c3 = cnt[nidx][4 * l + 3];
    int f0 = c0 != 0u, f1 = c1 != 0u, f2 = c2 != 0u, f3 = c3 != 0u;
    int nb = f0 + f1 + f2 + f3;
    int incl = nb;
    #pragma unroll
    for (int o = 1; o < 32; o <<= 1) {
        int u = __shfl_up(incl, o, 32);
        if (l >= o) incl += u;
    }
    int pos = incl - nb;
    int total = __shfl(incl, 31, 32);
    if (f0) { unsigned int cc = c0 > 10u ? 10u : c0;
              list[nidx][pos++] = (int)(((4 * l + 0) * 10 + (int)cc - 1) * 512); }
    if (f1) { unsigned int cc = c1 > 10u ? 10u : c1;
              list[nidx][pos++] = (int)(((4 * l + 1) * 10 + (int)cc - 1) * 512); }
    if (f2) { unsigned int cc = c2 > 10u ? 10u : c2;
              list[nidx][pos++] = (int)(((4 * l + 2) * 10 + (int)cc - 1) * 512); }
    if (f3) { unsigned int cc = c3 > 10u ? 10u : c3;
              list[nidx][pos++] = (int)(((4 * l + 3) * 10 + (int)cc - 1) * 512); }
    float4 acc;
    acc.x = wv.x + bs.x;
    acc.y = wv.y + bs.y;
    acc.z = wv.z + bs.z;
    acc.w = wv.w + bs.w;
    const char* Db = (const char*)Delta_l + l * 16;
    int i = 0;
    for (; i + 8 <= total; i += 8) {
        int o0 = list[nidx][i];
        int o1 = list[nidx][i + 1];
        int o2 = list[nidx][i + 2];
        int o3 = list[nidx][i + 3];
        int o4 = list[nidx][i + 4];
        int o5 = list[nidx][i + 5];
        int o6 = list[nidx][i + 6];
        int o7 = list[nidx][i + 7];
        float4 d0 = *(const float4*)(Db + o0);
        float4 d1 = *(const float4*)(Db + o1);
        float4 d2 = *(const float4*)(Db + o2);
        float4 d3 = *(const float4*)(Db + o3);
        float4 d4 = *(const float4*)(Db + o4);
        float4 d5 = *(const float4*)(Db + o5);
        float4 d6 = *(const float4*)(Db + o6);
        float4 d7 = *(const float4*)(Db + o7);
        acc.x += d0.x; acc.y += d0.y; acc.z += d0.z; acc.w += d0.w;
        acc.x += d1.x; acc.y += d1.y; acc.z += d1.z; acc.w += d1.w;
        acc.x += d2.x; acc.y += d2.y; acc.z += d2.z; acc.w += d2.w;
        acc.x += d3.x; acc.y += d3.y; acc.z += d3.z; acc.w += d3.w;
        acc.x += d4.x; acc.y += d4.y; acc.z += d4.z; acc.w += d4.w;
        acc.x += d5.x; acc.y += d5.y; acc.z += d5.z; acc.w += d5.w;
        acc.x += d6.x; acc.y += d6.y; acc.z += d6.z; acc.w += d6.w;
        acc.x += d7.x; acc.y += d7.y; acc.z += d7.z; acc.w += d7.w;
    }
    for (; i + 4 <= total; i += 4) {
        int o0 = list[nidx][i];
        int o1 = list[nidx][i + 1];
        int o2 = list[nidx][i + 2];
        int o3 = list[nidx][i + 3];
        float4 d0 = *(const float4*)(Db + o0);
        float4 d1 = *(const float4*)(Db + o1);
        float4 d2 = *(const float4*)(Db + o2);
        float4 d3 = *(const float4*)(Db + o3);
        acc.x += d0.x; acc.y += d0.y; acc.z += d0.z; acc.w += d0.w;
        acc.x += d1.x; acc.y += d1.y; acc.z += d1.z; acc.w += d1.w;
        acc.x += d2.x; acc.y += d2.y; acc.z += d2.z; acc.w += d2.w;
        acc.x += d3.x; acc.y += d3.y; acc.z += d3.z; acc.w += d3.w;
    }
    for (; i < total; ++i) {
        float4 dv = *(const float4*)(Db + list[nidx][i]);
        acc.x += dv.x; acc.y += dv.y; acc.z += dv.z; acc.w += dv.w;
    }
    acc.x += bb.x; acc.y += bb.y; acc.z += bb.z; acc.w += bb.w;
    float bv = acc.x; int bi = 4 * l;
    if (acc.y > bv) { bv = acc.y; bi = 4 * l + 1; }
    if (acc.z > bv) { bv = acc.z; bi = 4 * l + 2; }
    if (acc.w > bv) { bv = acc.w; bi = 4 * l + 3; }
    #pragma unroll
    for (int o = 16; o >= 1; o >>= 1) {
        float ov = __shfl_xor(bv, o);
        int oi = __shfl_xor(bi, o);
        if (ov > bv || (ov == bv && oi < bi)) { bv = ov; bi = oi; }
    }
    if (!LAST) {
        if (l == 0) idx_out[n] = bi;
        return;
    }
    // ---- fused output epilogue (layer 3) ----
    int r0 = id0, r1 = 128 + id1, r2 = 256 + id2, r3 = 384 + hidx, r4 = 512 + bi;
    float v0g = -INFINITY, v1g = -INFINITY;
    {
        int o = l;
        float a = W_out[(size_t)r0 * OUTD + o] + W_out[(size_t)r1 * OUTD + o]
                + W_out[(size_t)r2 * OUTD + o] + W_out[(size_t)r3 * OUTD + o]
                + W_out[(size_t)r4 * OUTD + o];
        v0g = a + b_out[o];
    }
    if (l < 8) {
        int o = 32 + l;
        float a = W_out[(size_t)r0 * OUTD + o] + W_out[(size_t)r1 * OUTD + o]
                + W_out[(size_t)r2 * OUTD + o] + W_out[(size_t)r3 * OUTD + o]
                + W_out[(size_t)r4 * OUTD + o];
        v1g = a + b_out[o];
    }
    float mx = fmaxf(v0g, v1g);
    #pragma unroll
    for (int o = 16; o >= 1; o >>= 1) mx = fmaxf(mx, __shfl_xor(mx, o, 32));
    float e0v = expf(v0g - mx);
    float e1v = (l < 8) ? expf(v1g - mx) : 0.0f;
    float se = e0v + e1v;
    #pragma unroll
    for (int o = 16; o >= 1; o >>= 1) se += __shfl_xor(se, o, 32);
    float lse = logf(se);
    out[(size_t)n * OUTD + l] = v0g - mx - lse;
    if (l < 8) out[(size_t)n * OUTD + 32 + l] = v1g - mx - lse;
}

extern "C" void kernel_launch(void* const* d_in, const int* in_sizes, int n_in,
                              void* d_out, int out_size, void* d_ws, size_t ws_size,
                              hipStream_t stream) {
    const float* x        = (const float*)d_in[0];
    const int*   edge     = (const int*)d_in[1];   // [2, E] int32
    const float* W_in     = (const float*)d_in[2];
    const float* b_in     = (const float*)d_in[3];
    const float* W_layers = (const float*)d_in[4]; // [4, 1408, 128]
    const float* b_layers = (const float*)d_in[5];
    const float* W_out    = (const float*)d_in[6]; // [640, 40]
    const float* b_out    = (const float*)d_in[7];
    float* out = (float*)d_out;

    char* ws = (char*)d_ws;
    size_t off = 0;
    float* Delta = (float*)(ws + off); off += (size_t)LL * 128 * 10 * 128 * 4;
    float* T0    = (float*)(ws + off); off += (size_t)LL * 128 * 128 * 4;
    float* Base  = (float*)(ws + off); off += (size_t)LL * 128 * 4;
    int*   idx   = (int*)(ws + off);   off += (size_t)(LL + 1) * NN * 4;
    unsigned int* cursor = (unsigned int*)(ws + off); off += (size_t)NN * 4;
    int*   slots = (int*)(ws + off);   off += (size_t)NN * MAXD * 4;

    const int* srcp = edge;
    const int* dstp = edge + NE;

    hipMemsetAsync(cursor, 0, (size_t)NN * 4, stream);
    hipLaunchKernelGGL(front_kernel, dim3(NB_IN + NB_T + NB_SC), dim3(256), 0, stream,
                       W_layers, T0, Delta, x, W_in, b_in, idx, srcp, dstp, cursor, slots);
    hipLaunchKernelGGL(build_Base, dim3(LL), dim3(128), 0, stream, T0, Base);

    for (int l = 0; l < 3; ++l) {
        hipLaunchKernelGGL(layer_kernel<false>, dim3(NN / 8), dim3(256), 0, stream,
                           cursor, slots,
                           W_layers + (size_t)l * 1408 * 128,
                           b_layers + (size_t)l * 128,
                           Delta + (size_t)l * 128 * 10 * 128,
                           Base + (size_t)l * 128,
                           idx + (size_t)l * NN,
                           idx + (size_t)(l + 1) * NN,
                           (const int*)nullptr, (const float*)nullptr,
                           (const float*)nullptr, (float*)nullptr);
    }
    hipLaunchKernelGGL(layer_kernel<true>, dim3(NN / 8), dim3(256), 0, stream,
                       cursor, slots,
                       W_layers + (size_t)3 * 1408 * 128,
                       b_layers + (size_t)3 * 128,
                       Delta + (size_t)3 * 128 * 10 * 128,
                       Base + (size_t)3 * 128,
                       idx + (size_t)3 * NN,
                       idx + (size_t)4 * NN,
                       idx, W_out, b_out, out);
}

// Round 23
// 182.873 us; speedup vs baseline: 1.1190x; 1.1190x over previous
//
#include <hip/hip_runtime.h>
#include <math.h>

#define NN 50000
#define NE 800000
#define DD 128
#define LL 4
#define OUTD 40
#define NB_IN ((NN + 63) / 64)               // 782 input blocks (dispatched FIRST)
#define NB_T 256                              // build_T blocks (2 rows each)
#define NB_SC ((NE + 1023) / 1024)           // 782 scatter blocks, 4 edges/thread
#define MAXD 64                               // fixed slot count per node (max deg ~45)

// S(t) = sigmoid(10*(elu(t) - 0.5)), matching jax.nn.elu (expm1) + sigmoid
__device__ __forceinline__ float S_func(float t) {
    float z = (t > 0.0f) ? t : expm1f(t);
    float xx = 10.0f * (z - 0.5f);
    return 1.0f / (1.0f + expf(-xx));
}

// ---- fused front kernel: input GEMM || build_T || single-pass slot scatter ----
// R23: exact restore of R20 (best measured, 185 us). R21 repacking: neutral.
// R22 32-node tile: regression (doubled barrier/staging overhead). R20's
// 64-node x 128-col, 4n x 8c, K-chunk 16 is the measured optimum.
__global__ __launch_bounds__(256) void front_kernel(
        const float* __restrict__ W_layers, float* __restrict__ T0,
        float* __restrict__ Delta,
        const float* __restrict__ x, const float* __restrict__ W_in,
        const float* __restrict__ b_in, int* __restrict__ idx0,
        const int* __restrict__ src, const int* __restrict__ dst,
        unsigned int* __restrict__ cursor, int* __restrict__ slots) {
    __shared__ float wlds[16][128];
    __shared__ float xls[64][20];
    int t = threadIdx.x;

    if (blockIdx.x >= NB_IN) {
        if (blockIdx.x < NB_IN + NB_T) {
            // ---- build_T: 2 (l,d) rows per block ----
            int bd = (blockIdx.x - NB_IN) * 2 + (t >> 7);
            int l = bd >> 7, d = bd & 127;
            int j = t & 127;
            const float* W2 = W_layers + ((size_t)l * 1408 + 128 + (size_t)d * 10) * 128;
            float w[10];
            #pragma unroll
            for (int y = 0; y < 10; ++y) w[y] = W2[(size_t)y * 128 + j];
            float t0 = 0.0f;
            #pragma unroll
            for (int y = 0; y < 10; ++y) t0 += S_func((float)(0 - y)) * w[y];
            T0[(size_t)bd * 128 + j] = t0;
            for (int c = 1; c <= 10; ++c) {
                float tc = 0.0f;
                #pragma unroll
                for (int y = 0; y < 10; ++y) tc += S_func((float)(c - y)) * w[y];
                Delta[((size_t)bd * 10 + (c - 1)) * 128 + j] = tc - t0;
            }
        } else {
            // ---- single-pass slot scatter, 4 edges/thread ----
            int e0 = (blockIdx.x - NB_IN - NB_T) * 1024 + t;
            #pragma unroll
            for (int k = 0; k < 4; ++k) {
                int e = e0 + k * 256;
                if (e < NE) {
                    int d = dst[e];
                    int s = src[e];
                    unsigned int pos = atomicAdd(&cursor[d], 1u);
                    if (pos < MAXD) slots[(size_t)d * MAXD + pos] = s;
                }
            }
        }
        return;
    }

    // ---- input GEMM: 64 nodes x 128 cols per block, 4 nodes x 8 cols/thread ----
    int bb = blockIdx.x;
    int cg = t & 15;
    int ng = t >> 4;
    int n0 = bb * 64;
    float acc[4][8];
    #pragma unroll
    for (int i = 0; i < 4; ++i)
        #pragma unroll
        for (int r = 0; r < 8; ++r) acc[i][r] = 0.0f;

    for (int kc = 0; kc < 8; ++kc) {
        __syncthreads();
        #pragma unroll
        for (int p = 0; p < 2; ++p) {
            int f = t + p * 256;
            int kr = f >> 5, c4 = f & 31;
            *(float4*)&wlds[kr][c4 * 4] =
                *(const float4*)&W_in[(size_t)(kc * 16 + kr) * 128 + c4 * 4];
        }
        {
            int node = t >> 2, k4 = t & 3;
            int gn = n0 + node;
            if (gn > NN - 1) gn = NN - 1;
            *(float4*)&xls[node][k4 * 4] =
                *(const float4*)&x[(size_t)gn * 128 + kc * 16 + k4 * 4];
        }
        __syncthreads();
        #pragma unroll
        for (int kk4 = 0; kk4 < 4; ++kk4) {
            float4 xv[4];
            #pragma unroll
            for (int i = 0; i < 4; ++i)
                xv[i] = *(const float4*)&xls[ng * 4 + i][kk4 * 4];
            #pragma unroll
            for (int q = 0; q < 4; ++q) {
                int k = kk4 * 4 + q;
                float4 w1 = *(const float4*)&wlds[k][cg * 4];
                float4 w2 = *(const float4*)&wlds[k][64 + cg * 4];
                #pragma unroll
                for (int i = 0; i < 4; ++i) {
                    float xvv = (q == 0) ? xv[i].x : (q == 1) ? xv[i].y
                              : (q == 2) ? xv[i].z : xv[i].w;
                    acc[i][0] = fmaf(xvv, w1.x, acc[i][0]);
                    acc[i][1] = fmaf(xvv, w1.y, acc[i][1]);
                    acc[i][2] = fmaf(xvv, w1.z, acc[i][2]);
                    acc[i][3] = fmaf(xvv, w1.w, acc[i][3]);
                    acc[i][4] = fmaf(xvv, w2.x, acc[i][4]);
                    acc[i][5] = fmaf(xvv, w2.y, acc[i][5]);
                    acc[i][6] = fmaf(xvv, w2.z, acc[i][6]);
                    acc[i][7] = fmaf(xvv, w2.w, acc[i][7]);
                }
            }
        }
    }
    float4 b1 = *(const float4*)&b_in[cg * 4];
    float4 b2 = *(const float4*)&b_in[64 + cg * 4];
    #pragma unroll
    for (int i = 0; i < 4; ++i) {
        float v0 = acc[i][0] + b1.x, v1 = acc[i][1] + b1.y;
        float v2 = acc[i][2] + b1.z, v3 = acc[i][3] + b1.w;
        float v4 = acc[i][4] + b2.x, v5 = acc[i][5] + b2.y;
        float v6 = acc[i][6] + b2.z, v7 = acc[i][7] + b2.w;
        float bv = v0; int bi = cg * 4;
        if (v1 > bv) { bv = v1; bi = cg * 4 + 1; }
        if (v2 > bv) { bv = v2; bi = cg * 4 + 2; }
        if (v3 > bv) { bv = v3; bi = cg * 4 + 3; }
        if (v4 > bv) { bv = v4; bi = 64 + cg * 4; }
        if (v5 > bv) { bv = v5; bi = 64 + cg * 4 + 1; }
        if (v6 > bv) { bv = v6; bi = 64 + cg * 4 + 2; }
        if (v7 > bv) { bv = v7; bi = 64 + cg * 4 + 3; }
        #pragma unroll
        for (int o = 8; o >= 1; o >>= 1) {
            float ov = __shfl_xor(bv, o);
            int oi = __shfl_xor(bi, o);
            if (ov > bv || (ov == bv && oi < bi)) { bv = ov; bi = oi; }
        }
        int n = n0 + ng * 4 + i;
        if (cg == 0 && n < NN) idx0[n] = bi;
    }
}

__global__ void build_Base(const float* __restrict__ T0, float* __restrict__ Base) {
    int l = blockIdx.x, j = threadIdx.x;
    float s = 0.0f;
    for (int d = 0; d < 128; ++d) s += T0[((size_t)l * 128 + d) * 128 + j];
    Base[l * 128 + j] = s;
}

// ---- fused per-layer kernel: half-wave (32 lanes) per node, 8 nodes/block.
// cnt accessed ONLY as scalar uint (R3 TBAA lesson); per-half-wave phases
// syncless. LAST fuses the 40-logit log_softmax epilogue.
template<bool LAST>
__global__ __launch_bounds__(256) void layer_kernel(
        const unsigned int* __restrict__ cursor, const int* __restrict__ slots,
        const float* __restrict__ Wl, const float* __restrict__ bl,
        const float* __restrict__ Delta_l, const float* __restrict__ Base_l,
        const int* __restrict__ idx_in, int* __restrict__ idx_out,
        const int* __restrict__ idx_all, const float* __restrict__ W_out,
        const float* __restrict__ b_out, float* __restrict__ out) {
    __shared__ unsigned int cnt[8][128];
    __shared__ int list[8][128];
    int w = threadIdx.x >> 6;
    int lane = threadIdx.x & 63;
    int h = lane >> 5, l = lane & 31;
    int nidx = w * 2 + h;
    int n = blockIdx.x * 8 + nidx;
    unsigned int deg = cursor[n];
    if (deg > MAXD) deg = MAXD;
    int hidx = idx_in[n];
    int id0, id1, id2;
    if (LAST) {
        id0 = idx_all[n];
        id1 = idx_all[NN + n];
        id2 = idx_all[2 * NN + n];
    }
    float4 wv = *(const float4*)((const char*)Wl + (size_t)hidx * 512 + l * 16);
    float4 bs = *(const float4*)((const char*)Base_l + l * 16);
    float4 bb = *(const float4*)((const char*)bl + l * 16);
    cnt[nidx][l]      = 0u;
    cnt[nidx][l + 32] = 0u;
    cnt[nidx][l + 64] = 0u;
    cnt[nidx][l + 96] = 0u;
    const int* srow = slots + (size_t)n * MAXD;
    for (unsigned int e = l; e < deg; e += 32u) {
        int s = srow[e];
        atomicAdd(&cnt[nidx][idx_in[s]], 1u);
    }
    unsigned int c0 = cnt[nidx][4 * l];
    unsigned int c1 = cnt[nidx][4 * l + 1];
    unsigned int c2 = cnt[nidx][4 * l + 2];
    unsigned int c3 = cnt[nidx][4 * l + 3];
    int f0 = c0 != 0u, f1 = c1 != 0u, f2 = c2 != 0u, f3 = c3 != 0u;
    int nb = f0 + f1 + f2 + f3;
    int incl = nb;
    #pragma unroll
    for (int o = 1; o < 32; o <<= 1) {
        int u = __shfl_up(incl, o, 32);
        if (l >= o) incl += u;
    }
    int pos = incl - nb;
    int total = __shfl(incl, 31, 32);
    if (f0) { unsigned int cc = c0 > 10u ? 10u : c0;
              list[nidx][pos++] = (int)(((4 * l + 0) * 10 + (int)cc - 1) * 512); }
    if (f1) { unsigned int cc = c1 > 10u ? 10u : c1;
              list[nidx][pos++] = (int)(((4 * l + 1) * 10 + (int)cc - 1) * 512); }
    if (f2) { unsigned int cc = c2 > 10u ? 10u : c2;
              list[nidx][pos++] = (int)(((4 * l + 2) * 10 + (int)cc - 1) * 512); }
    if (f3) { unsigned int cc = c3 > 10u ? 10u : c3;
              list[nidx][pos++] = (int)(((4 * l + 3) * 10 + (int)cc - 1) * 512); }
    float4 acc;
    acc.x = wv.x + bs.x;
    acc.y = wv.y + bs.y;
    acc.z = wv.z + bs.z;
    acc.w = wv.w + bs.w;
    const char* Db = (const char*)Delta_l + l * 16;
    int i = 0;
    for (; i + 8 <= total; i += 8) {
        int o0 = list[nidx][i];
        int o1 = list[nidx][i + 1];
        int o2 = list[nidx][i + 2];
        int o3 = list[nidx][i + 3];
        int o4 = list[nidx][i + 4];
        int o5 = list[nidx][i + 5];
        int o6 = list[nidx][i + 6];
        int o7 = list[nidx][i + 7];
        float4 d0 = *(const float4*)(Db + o0);
        float4 d1 = *(const float4*)(Db + o1);
        float4 d2 = *(const float4*)(Db + o2);
        float4 d3 = *(const float4*)(Db + o3);
        float4 d4 = *(const float4*)(Db + o4);
        float4 d5 = *(const float4*)(Db + o5);
        float4 d6 = *(const float4*)(Db + o6);
        float4 d7 = *(const float4*)(Db + o7);
        acc.x += d0.x; acc.y += d0.y; acc.z += d0.z; acc.w += d0.w;
        acc.x += d1.x; acc.y += d1.y; acc.z += d1.z; acc.w += d1.w;
        acc.x += d2.x; acc.y += d2.y; acc.z += d2.z; acc.w += d2.w;
        acc.x += d3.x; acc.y += d3.y; acc.z += d3.z; acc.w += d3.w;
        acc.x += d4.x; acc.y += d4.y; acc.z += d4.z; acc.w += d4.w;
        acc.x += d5.x; acc.y += d5.y; acc.z += d5.z; acc.w += d5.w;
        acc.x += d6.x; acc.y += d6.y; acc.z += d6.z; acc.w += d6.w;
        acc.x += d7.x; acc.y += d7.y; acc.z += d7.z; acc.w += d7.w;
    }
    for (; i + 4 <= total; i += 4) {
        int o0 = list[nidx][i];
        int o1 = list[nidx][i + 1];
        int o2 = list[nidx][i + 2];
        int o3 = list[nidx][i + 3];
        float4 d0 = *(const float4*)(Db + o0);
        float4 d1 = *(const float4*)(Db + o1);
        float4 d2 = *(const float4*)(Db + o2);
        float4 d3 = *(const float4*)(Db + o3);
        acc.x += d0.x; acc.y += d0.y; acc.z += d0.z; acc.w += d0.w;
        acc.x += d1.x; acc.y += d1.y; acc.z += d1.z; acc.w += d1.w;
        acc.x += d2.x; acc.y += d2.y; acc.z += d2.z; acc.w += d2.w;
        acc.x += d3.x; acc.y += d3.y; acc.z += d3.z; acc.w += d3.w;
    }
    for (; i < total; ++i) {
        float4 dv = *(const float4*)(Db + list[nidx][i]);
        acc.x += dv.x; acc.y += dv.y; acc.z += dv.z; acc.w += dv.w;
    }
    acc.x += bb.x; acc.y += bb.y; acc.z += bb.z; acc.w += bb.w;
    float bv = acc.x; int bi = 4 * l;
    if (acc.y > bv) { bv = acc.y; bi = 4 * l + 1; }
    if (acc.z > bv) { bv = acc.z; bi = 4 * l + 2; }
    if (acc.w > bv) { bv = acc.w; bi = 4 * l + 3; }
    #pragma unroll
    for (int o = 16; o >= 1; o >>= 1) {
        float ov = __shfl_xor(bv, o);
        int oi = __shfl_xor(bi, o);
        if (ov > bv || (ov == bv && oi < bi)) { bv = ov; bi = oi; }
    }
    if (!LAST) {
        if (l == 0) idx_out[n] = bi;
        return;
    }
    // ---- fused output epilogue (layer 3) ----
    int r0 = id0, r1 = 128 + id1, r2 = 256 + id2, r3 = 384 + hidx, r4 = 512 + bi;
    float v0g = -INFINITY, v1g = -INFINITY;
    {
        int o = l;
        float a = W_out[(size_t)r0 * OUTD + o] + W_out[(size_t)r1 * OUTD + o]
                + W_out[(size_t)r2 * OUTD + o] + W_out[(size_t)r3 * OUTD + o]
                + W_out[(size_t)r4 * OUTD + o];
        v0g = a + b_out[o];
    }
    if (l < 8) {
        int o = 32 + l;
        float a = W_out[(size_t)r0 * OUTD + o] + W_out[(size_t)r1 * OUTD + o]
                + W_out[(size_t)r2 * OUTD + o] + W_out[(size_t)r3 * OUTD + o]
                + W_out[(size_t)r4 * OUTD + o];
        v1g = a + b_out[o];
    }
    float mx = fmaxf(v0g, v1g);
    #pragma unroll
    for (int o = 16; o >= 1; o >>= 1) mx = fmaxf(mx, __shfl_xor(mx, o, 32));
    float e0v = expf(v0g - mx);
    float e1v = (l < 8) ? expf(v1g - mx) : 0.0f;
    float se = e0v + e1v;
    #pragma unroll
    for (int o = 16; o >= 1; o >>= 1) se += __shfl_xor(se, o, 32);
    float lse = logf(se);
    out[(size_t)n * OUTD + l] = v0g - mx - lse;
    if (l < 8) out[(size_t)n * OUTD + 32 + l] = v1g - mx - lse;
}

extern "C" void kernel_launch(void* const* d_in, const int* in_sizes, int n_in,
                              void* d_out, int out_size, void* d_ws, size_t ws_size,
                              hipStream_t stream) {
    const float* x        = (const float*)d_in[0];
    const int*   edge     = (const int*)d_in[1];   // [2, E] int32
    const float* W_in     = (const float*)d_in[2];
    const float* b_in     = (const float*)d_in[3];
    const float* W_layers = (const float*)d_in[4]; // [4, 1408, 128]
    const float* b_layers = (const float*)d_in[5];
    const float* W_out    = (const float*)d_in[6]; // [640, 40]
    const float* b_out    = (const float*)d_in[7];
    float* out = (float*)d_out;

    char* ws = (char*)d_ws;
    size_t off = 0;
    float* Delta = (float*)(ws + off); off += (size_t)LL * 128 * 10 * 128 * 4;
    float* T0    = (float*)(ws + off); off += (size_t)LL * 128 * 128 * 4;
    float* Base  = (float*)(ws + off); off += (size_t)LL * 128 * 4;
    int*   idx   = (int*)(ws + off);   off += (size_t)(LL + 1) * NN * 4;
    unsigned int* cursor = (unsigned int*)(ws + off); off += (size_t)NN * 4;
    int*   slots = (int*)(ws + off);   off += (size_t)NN * MAXD * 4;

    const int* srcp = edge;
    const int* dstp = edge + NE;

    hipMemsetAsync(cursor, 0, (size_t)NN * 4, stream);
    hipLaunchKernelGGL(front_kernel, dim3(NB_IN + NB_T + NB_SC), dim3(256), 0, stream,
                       W_layers, T0, Delta, x, W_in, b_in, idx, srcp, dstp, cursor, slots);
    hipLaunchKernelGGL(build_Base, dim3(LL), dim3(128), 0, stream, T0, Base);

    for (int l = 0; l < 3; ++l) {
        hipLaunchKernelGGL(layer_kernel<false>, dim3(NN / 8), dim3(256), 0, stream,
                           cursor, slots,
                           W_layers + (size_t)l * 1408 * 128,
                           b_layers + (size_t)l * 128,
                           Delta + (size_t)l * 128 * 10 * 128,
                           Base + (size_t)l * 128,
                           idx + (size_t)l * NN,
                           idx + (size_t)(l + 1) * NN,
                           (const int*)nullptr, (const float*)nullptr,
                           (const float*)nullptr, (float*)nullptr);
    }
    hipLaunchKernelGGL(layer_kernel<true>, dim3(NN / 8), dim3(256), 0, stream,
                       cursor, slots,
                       W_layers + (size_t)3 * 1408 * 128,
                       b_layers + (size_t)3 * 128,
                       Delta + (size_t)3 * 128 * 10 * 128,
                       Base + (size_t)3 * 128,
                       idx + (size_t)3 * NN,
                       idx + (size_t)4 * NN,
                       idx, W_out, b_out, out);
}